// Round 4
// baseline (278.245 us; speedup 1.0000x reference)
//
#include <hip/hip_runtime.h>
#include <hip/hip_cooperative_groups.h>
#include <math.h>

namespace cg = cooperative_groups;

#define NWAVE 8
#define NTYPE 4
#define CAP   256   // payload slots per atom bin (fan-in ~Poisson(40); P(>256)~0)

// ---------------------------------------------------------------------------
// R4: single cooperative kernel. R3 spent ~105us across 5 dependent graph
// dispatches whose work sums to ~35us; the harness's 256MiB ws 0xAA-poison
// (40.5us fill) is a fixed floor. Fixed-capacity bins kill count+scan.
// Phases: zero cursors -> bin edges (atomic cursor) -> per-atom wave gather.
// ---------------------------------------------------------------------------
__global__ void __launch_bounds__(256, 2)
fused_density_kernel(const float* __restrict__ cart,      // (B*N,3)
                     const int*   __restrict__ species,   // (B*N,)
                     const int*   __restrict__ atom_index,// (2,B,P)
                     const float* __restrict__ shifts,    // (B,P,3)
                     const float* __restrict__ rs,        // (4,8)
                     const float* __restrict__ inta,      // (4,8)
                     const float* __restrict__ params,    // (4,24)
                     const float* __restrict__ hyper,     // (3,8,8)
                     int*         __restrict__ cursors,   // (T,)
                     float4*      __restrict__ payload,   // (T,CAP)
                     float*       __restrict__ out,       // (T,24)
                     int B, int P, int N)
{
    cg::grid_group grid = cg::this_grid();
    const int T = B * N;
    const int g = blockIdx.x * blockDim.x + threadIdx.x;
    const int G = gridDim.x * blockDim.x;

    __shared__ float sh_rs[NTYPE * NWAVE];
    __shared__ float sh_inta[NTYPE * NWAVE];
    if (threadIdx.x < 32) {
        sh_rs[threadIdx.x]   = rs[threadIdx.x];
        sh_inta[threadIdx.x] = inta[threadIdx.x];
    }
    __syncthreads();

    // ---- phase 0: zero bin cursors (ws is poisoned 0xAA every iteration)
    for (int t = g; t < T; t += G) cursors[t] = 0;
    grid.sync();

    // ---- phase 1: bin edges (geometry computed once here)
    const int BP = B * P;
    for (int b = 0; b < B; ++b) {
        const int base = b * N;
        const int*   __restrict__ ai0 = atom_index + (size_t)b * P;
        const int*   __restrict__ ai1 = atom_index + (size_t)BP + (size_t)b * P;
        const float* __restrict__ sh  = shifts + (size_t)b * P * 3;
        for (int p = g; p < P; p += G) {
            int i0 = ai0[p] + base;
            int i1 = ai1[p] + base;
            float dx = cart[3 * i0 + 0] - cart[3 * i1 + 0] + sh[3 * p + 0];
            float dy = cart[3 * i0 + 1] - cart[3 * i1 + 1] + sh[3 * p + 1];
            float dz = cart[3 * i0 + 2] - cart[3 * i1 + 2] + sh[3 * p + 2];
            int sp = species[i1];
            int pos = atomicAdd(&cursors[i0], 1);
            if (pos < CAP)
                payload[(size_t)i0 * CAP + pos] =
                    make_float4(dx, dy, dz, __int_as_float(sp));
        }
    }
    __threadfence();
    grid.sync();

    // ---- phase 2: per-atom gather, one wave per atom
    const int lane = threadIdx.x & 63;
    const int s    = lane >> 3;   // edge slice 0..7
    const int m    = lane & 7;    // wave channel 0..7
    const int w    = g >> 6;      // global wave id
    const int NW   = G >> 6;      // total waves

    float hcol0[8], hcol1[8], hcol2[8];
#pragma unroll
    for (int k = 0; k < 8; ++k) {
        hcol0[k] = hyper[       k * 8 + m];
        hcol1[k] = hyper[ 64 +  k * 8 + m];
        hcol2[k] = hyper[128 +  k * 8 + m];
    }
    float par[NTYPE][3];
#pragma unroll
    for (int sp = 0; sp < NTYPE; ++sp)
#pragma unroll
        for (int p = 0; p < 3; ++p)
            par[sp][p] = params[sp * 24 + p * 8 + m];

    for (int t = w; t < T; t += NW) {
        int cnt = cursors[t];
        if (cnt > CAP) cnt = CAP;
        const float4* __restrict__ pl = payload + (size_t)t * CAP;

        float a0 = 0.f;
        float a1x = 0.f, a1y = 0.f, a1z = 0.f;
        float axx = 0.f, ayy = 0.f, azz = 0.f;
        float axy = 0.f, axz = 0.f, ayz = 0.f;

        for (int i = s; i < cnt; i += 8) {
            float4 d = pl[i];
            int sp = __float_as_int(d.w);
            float dx = d.x, dy = d.y, dz = d.z;
            float dist = sqrtf(dx * dx + dy * dy + dz * dz);
            float inv = 1.0f / dist;
            float ux = dx * inv, uy = dy * inv, uz = dz * inv;
            float fc = 0.5f * __cosf(dist * (float)(M_PI / 5.0)) + 0.5f;
            fc = fc * fc;
            float r0 = 0.f, r1 = 0.f, r2 = 0.f;
#pragma unroll
            for (int k = 0; k < 8; ++k) {
                float dd = dist - sh_rs[sp * 8 + k];
                float rad = __expf(-sh_inta[sp * 8 + k] * dd * dd);
                r0 += rad * hcol0[k];
                r1 += rad * hcol1[k];
                r2 += rad * hcol2[k];
            }
            float W0 = fc * r0 * par[sp][0];
            float W1 = fc * r1 * par[sp][1];
            float W2 = fc * r2 * par[sp][2];
            a0 += W0;
            a1x += ux * W1; a1y += uy * W1; a1z += uz * W1;
            float tx = ux * W2, ty = uy * W2;
            axx += tx * ux; axy += tx * uy; axz += tx * uz;
            ayy += ty * uy; ayz += ty * uz;
            azz += uz * uz * W2;
        }

#define RED(v) v += __shfl_xor(v, 8); v += __shfl_xor(v, 16); v += __shfl_xor(v, 32)
        RED(a0);
        RED(a1x); RED(a1y); RED(a1z);
        RED(axx); RED(ayy); RED(azz); RED(axy); RED(axz); RED(ayz);
#undef RED

        if (s == 0) {
            float o0 = a0 * a0;
            float o1 = a1x * a1x + a1y * a1y + a1z * a1z;
            float o2 = axx * axx + ayy * ayy + azz * azz
                     + 2.0f * (axy * axy + axz * axz + ayz * ayz);
            float* o = out + (size_t)t * 24;
            o[m] = o0; o[8 + m] = o1; o[16 + m] = o2;
        }
    }
}

// ---------------------------------------------------------------------------
extern "C" void kernel_launch(void* const* d_in, const int* in_sizes, int n_in,
                              void* d_out, int out_size, void* d_ws, size_t ws_size,
                              hipStream_t stream)
{
    const float* cart       = (const float*)d_in[0];
    const int*   species    = (const int*)  d_in[2];
    const int*   atom_index = (const int*)  d_in[3];
    const float* shifts     = (const float*)d_in[4];
    const float* rs         = (const float*)d_in[5];
    const float* inta       = (const float*)d_in[6];
    const float* params     = (const float*)d_in[7];
    const float* hyper      = (const float*)d_in[8];

    int B  = in_sizes[1];            // 8
    int N  = in_sizes[2] / B;        // 1000
    int BP = in_sizes[3] / 2;        // 320000
    int P  = BP / B;                 // 40000
    int T  = B * N;                  // 8000

    char* ws = (char*)d_ws;
    float4* payload = (float4*)ws;                          // T*CAP*16 = 32.8 MB
    int*    cursors = (int*)(ws + (size_t)T * CAP * 16);    // T ints
    float*  out     = (float*)d_out;

    void* args[] = { (void*)&cart, (void*)&species, (void*)&atom_index,
                     (void*)&shifts, (void*)&rs, (void*)&inta, (void*)&params,
                     (void*)&hyper, (void*)&cursors, (void*)&payload,
                     (void*)&out, (void*)&B, (void*)&P, (void*)&N };

    // 512 blocks x 256 threads = 2 blocks/CU — co-residency guaranteed
    hipLaunchCooperativeKernel((const void*)fused_density_kernel,
                               dim3(512), dim3(256), args, 0, stream);
}

// Round 5
// 117.938 us; speedup vs baseline: 2.3592x; 2.3592x over previous
//
#include <hip/hip_runtime.h>
#include <math.h>

#define NWAVE 8
#define NTYPE 4
#define CAP   256   // payload slots per atom bin (fan-in ~Poisson(40); P(>CAP)~1e-80)

// ---------------------------------------------------------------------------
// R5: back to plain graph-node pipeline (R4 cooperative fusion was 3x slower:
// starved phase-1, expensive grid.sync, 8-wave/CU cap). Fixed-capacity bins
// (the one good R4 idea) delete count+scan: memset(32KB) -> fill -> gather.
// ---------------------------------------------------------------------------

// Kernel 1: one edge per thread; geometry once; bin by center atom.
__global__ void __launch_bounds__(256)
fill_binned_kernel(const float* __restrict__ cart,      // (B*N,3)
                   const int*   __restrict__ species,   // (B*N,)
                   const int*   __restrict__ atom_index,// (2,B,P)
                   const float* __restrict__ shifts,    // (B,P,3)
                   int*         __restrict__ cursors,   // (T,) pre-zeroed
                   float4*      __restrict__ payload,   // (T,CAP)
                   int BP, int P, int N)
{
    int e = blockIdx.x * 256 + threadIdx.x;
    if (e >= BP) return;
    int b = e / P, base = b * N;
    int i0 = atom_index[e] + base;
    int i1 = atom_index[BP + e] + base;
    float dx = cart[3 * i0 + 0] - cart[3 * i1 + 0] + shifts[3 * e + 0];
    float dy = cart[3 * i0 + 1] - cart[3 * i1 + 1] + shifts[3 * e + 1];
    float dz = cart[3 * i0 + 2] - cart[3 * i1 + 2] + shifts[3 * e + 2];
    int sp = species[i1];
    int pos = atomicAdd(&cursors[i0], 1);
    if (pos < CAP)
        payload[(size_t)i0 * CAP + pos] = make_float4(dx, dy, dz, __int_as_float(sp));
}

// Kernel 2: one wave per atom. lane = slice*8 + m; slices stride the bin;
// butterfly-reduce over slice bits (8,16,32); slice 0 writes 24 outputs.
__global__ void __launch_bounds__(256)
atom_gather_kernel(const float4* __restrict__ payload,
                   const int* __restrict__ cursors,
                   const float* __restrict__ rs,     // (4,8)
                   const float* __restrict__ inta,   // (4,8)
                   const float* __restrict__ params, // (4,24)
                   const float* __restrict__ hyper,  // (3,8,8)
                   float* __restrict__ out, int T)
{
    __shared__ float sh_rs[NTYPE * NWAVE];
    __shared__ float sh_inta[NTYPE * NWAVE];
    int tid = threadIdx.x;
    if (tid < 32) { sh_rs[tid] = rs[tid]; sh_inta[tid] = inta[tid]; }
    __syncthreads();

    int t    = blockIdx.x * 4 + (tid >> 6);
    int lane = tid & 63;
    int s    = lane >> 3;    // edge slice 0..7
    int m    = lane & 7;     // wave channel 0..7
    if (t >= T) return;

    float hcol0[8], hcol1[8], hcol2[8];
#pragma unroll
    for (int k = 0; k < 8; ++k) {
        hcol0[k] = hyper[       k * 8 + m];
        hcol1[k] = hyper[ 64 +  k * 8 + m];
        hcol2[k] = hyper[128 +  k * 8 + m];
    }
    float par[NTYPE][3];
#pragma unroll
    for (int sp = 0; sp < NTYPE; ++sp)
#pragma unroll
        for (int p = 0; p < 3; ++p)
            par[sp][p] = params[sp * 24 + p * 8 + m];

    int cnt = cursors[t];
    if (cnt > CAP) cnt = CAP;
    const float4* __restrict__ pl = payload + (size_t)t * CAP;

    float a0 = 0.f;
    float a1x = 0.f, a1y = 0.f, a1z = 0.f;
    float axx = 0.f, ayy = 0.f, azz = 0.f, axy = 0.f, axz = 0.f, ayz = 0.f;

    for (int i = s; i < cnt; i += 8) {
        float4 d = pl[i];
        int sp = __float_as_int(d.w);
        float dx = d.x, dy = d.y, dz = d.z;
        float dist = sqrtf(dx * dx + dy * dy + dz * dz);
        float inv = 1.0f / dist;
        float ux = dx * inv, uy = dy * inv, uz = dz * inv;
        float fc = 0.5f * __cosf(dist * (float)(M_PI / 5.0)) + 0.5f;
        fc = fc * fc;
        float r0 = 0.f, r1 = 0.f, r2 = 0.f;
#pragma unroll
        for (int k = 0; k < 8; ++k) {
            float dd = dist - sh_rs[sp * 8 + k];
            float rad = __expf(-sh_inta[sp * 8 + k] * dd * dd);
            r0 += rad * hcol0[k];
            r1 += rad * hcol1[k];
            r2 += rad * hcol2[k];
        }
        float W0 = fc * r0 * par[sp][0];
        float W1 = fc * r1 * par[sp][1];
        float W2 = fc * r2 * par[sp][2];
        a0 += W0;
        a1x += ux * W1; a1y += uy * W1; a1z += uz * W1;
        float tx = ux * W2, ty = uy * W2;
        axx += tx * ux; axy += tx * uy; axz += tx * uz;
        ayy += ty * uy; ayz += ty * uz;
        azz += uz * uz * W2;
    }

#define RED(v) v += __shfl_xor(v, 8); v += __shfl_xor(v, 16); v += __shfl_xor(v, 32)
    RED(a0);
    RED(a1x); RED(a1y); RED(a1z);
    RED(axx); RED(ayy); RED(azz); RED(axy); RED(axz); RED(ayz);
#undef RED

    if (s == 0) {
        float o0 = a0 * a0;
        float o1 = a1x * a1x + a1y * a1y + a1z * a1z;
        float o2 = axx * axx + ayy * ayy + azz * azz
                 + 2.0f * (axy * axy + axz * axz + ayz * ayz);
        float* o = out + (size_t)t * 24;
        o[m] = o0; o[8 + m] = o1; o[16 + m] = o2;
    }
}

// ---------------------------------------------------------------------------
extern "C" void kernel_launch(void* const* d_in, const int* in_sizes, int n_in,
                              void* d_out, int out_size, void* d_ws, size_t ws_size,
                              hipStream_t stream)
{
    const float* cart       = (const float*)d_in[0];
    const int*   species    = (const int*)  d_in[2];
    const int*   atom_index = (const int*)  d_in[3];
    const float* shifts     = (const float*)d_in[4];
    const float* rs         = (const float*)d_in[5];
    const float* inta       = (const float*)d_in[6];
    const float* params     = (const float*)d_in[7];
    const float* hyper      = (const float*)d_in[8];

    const int B  = in_sizes[1];          // 8
    const int N  = in_sizes[2] / B;      // 1000
    const int BP = in_sizes[3] / 2;      // 320000
    const int P  = BP / B;               // 40000
    const int T  = B * N;                // 8000

    char* ws = (char*)d_ws;
    float4* payload = (float4*)ws;                       // T*CAP*16 = 32.8 MB
    int*    cursors = (int*)(ws + (size_t)T * CAP * 16); // T ints

    hipMemsetAsync(cursors, 0, (size_t)T * sizeof(int), stream);

    fill_binned_kernel<<<(BP + 255) / 256, 256, 0, stream>>>(
        cart, species, atom_index, shifts, cursors, payload, BP, P, N);

    atom_gather_kernel<<<(T + 3) / 4, 256, 0, stream>>>(
        payload, cursors, rs, inta, params, hyper, (float*)d_out, T);
}

// Round 6
// 115.893 us; speedup vs baseline: 2.4009x; 1.0177x over previous
//
#include <hip/hip_runtime.h>
#include <math.h>

#define NWAVE 8
#define NTYPE 4
#define CAP   256   // payload slots per atom bin (fan-in ~Poisson(40); P(>CAP)~1e-80)

// ---------------------------------------------------------------------------
// R6: R5 pipeline (memset 32KB -> fill_binned -> gather), micro-optimized.
// R5 profile: top-5 dispatches are ALL the harness's 256MiB ws 0xAA-poison
// (41us each) -> our kernels are each <40us; controllable budget ~30us.
// Changes: 2D grid kills per-thread div by runtime P in fill; hoisted loads.
// ---------------------------------------------------------------------------

// Kernel 1: one edge per thread; geometry once; bin by center atom.
// grid = (ceil(P/256), B); molecule id = blockIdx.y (no integer division).
__global__ void __launch_bounds__(256)
fill_binned_kernel(const float* __restrict__ cart,      // (B*N,3)
                   const int*   __restrict__ species,   // (B*N,)
                   const int*   __restrict__ atom_index,// (2,B,P)
                   const float* __restrict__ shifts,    // (B,P,3)
                   int*         __restrict__ cursors,   // (T,) pre-zeroed
                   float4*      __restrict__ payload,   // (T,CAP)
                   int BP, int P, int N)
{
    const int p = blockIdx.x * 256 + threadIdx.x;
    if (p >= P) return;
    const int b = blockIdx.y;
    const int e = b * P + p;
    const int base = b * N;

    // issue all loads up front (independent) so VMEM latency overlaps
    const int i0 = atom_index[e] + base;
    const int i1 = atom_index[BP + e] + base;
    const float sx = shifts[3 * e + 0];
    const float sy = shifts[3 * e + 1];
    const float sz = shifts[3 * e + 2];
    const float c0x = cart[3 * i0 + 0], c0y = cart[3 * i0 + 1], c0z = cart[3 * i0 + 2];
    const float c1x = cart[3 * i1 + 0], c1y = cart[3 * i1 + 1], c1z = cart[3 * i1 + 2];
    const int sp = species[i1];

    const float dx = c0x - c1x + sx;
    const float dy = c0y - c1y + sy;
    const float dz = c0z - c1z + sz;

    const int pos = atomicAdd(&cursors[i0], 1);
    if (pos < CAP)
        payload[(size_t)i0 * CAP + pos] = make_float4(dx, dy, dz, __int_as_float(sp));
}

// Kernel 2: one wave per atom. lane = slice*8 + m; slices stride the bin;
// butterfly-reduce over slice bits (8,16,32); slice 0 writes 24 outputs.
__global__ void __launch_bounds__(256)
atom_gather_kernel(const float4* __restrict__ payload,
                   const int* __restrict__ cursors,
                   const float* __restrict__ rs,     // (4,8)
                   const float* __restrict__ inta,   // (4,8)
                   const float* __restrict__ params, // (4,24)
                   const float* __restrict__ hyper,  // (3,8,8)
                   float* __restrict__ out, int T)
{
    __shared__ float sh_rs[NTYPE * NWAVE];
    __shared__ float sh_inta[NTYPE * NWAVE];
    int tid = threadIdx.x;
    if (tid < 32) { sh_rs[tid] = rs[tid]; sh_inta[tid] = inta[tid]; }
    __syncthreads();

    int t    = blockIdx.x * 4 + (tid >> 6);
    int lane = tid & 63;
    int s    = lane >> 3;    // edge slice 0..7
    int m    = lane & 7;     // wave channel 0..7
    if (t >= T) return;

    float hcol0[8], hcol1[8], hcol2[8];
#pragma unroll
    for (int k = 0; k < 8; ++k) {
        hcol0[k] = hyper[       k * 8 + m];
        hcol1[k] = hyper[ 64 +  k * 8 + m];
        hcol2[k] = hyper[128 +  k * 8 + m];
    }
    float par[NTYPE][3];
#pragma unroll
    for (int sp = 0; sp < NTYPE; ++sp)
#pragma unroll
        for (int p = 0; p < 3; ++p)
            par[sp][p] = params[sp * 24 + p * 8 + m];

    int cnt = cursors[t];
    if (cnt > CAP) cnt = CAP;
    const float4* __restrict__ pl = payload + (size_t)t * CAP;

    float a0 = 0.f;
    float a1x = 0.f, a1y = 0.f, a1z = 0.f;
    float axx = 0.f, ayy = 0.f, azz = 0.f, axy = 0.f, axz = 0.f, ayz = 0.f;

    for (int i = s; i < cnt; i += 8) {
        float4 d = pl[i];
        int sp = __float_as_int(d.w);
        float dx = d.x, dy = d.y, dz = d.z;
        float dist = sqrtf(dx * dx + dy * dy + dz * dz);
        float inv = 1.0f / dist;
        float ux = dx * inv, uy = dy * inv, uz = dz * inv;
        float fc = 0.5f * __cosf(dist * (float)(M_PI / 5.0)) + 0.5f;
        fc = fc * fc;
        float r0 = 0.f, r1 = 0.f, r2 = 0.f;
#pragma unroll
        for (int k = 0; k < 8; ++k) {
            float dd = dist - sh_rs[sp * 8 + k];
            float rad = __expf(-sh_inta[sp * 8 + k] * dd * dd);
            r0 += rad * hcol0[k];
            r1 += rad * hcol1[k];
            r2 += rad * hcol2[k];
        }
        float W0 = fc * r0 * par[sp][0];
        float W1 = fc * r1 * par[sp][1];
        float W2 = fc * r2 * par[sp][2];
        a0 += W0;
        a1x += ux * W1; a1y += uy * W1; a1z += uz * W1;
        float tx = ux * W2, ty = uy * W2;
        axx += tx * ux; axy += tx * uy; axz += tx * uz;
        ayy += ty * uy; ayz += ty * uz;
        azz += uz * uz * W2;
    }

#define RED(v) v += __shfl_xor(v, 8); v += __shfl_xor(v, 16); v += __shfl_xor(v, 32)
    RED(a0);
    RED(a1x); RED(a1y); RED(a1z);
    RED(axx); RED(ayy); RED(azz); RED(axy); RED(axz); RED(ayz);
#undef RED

    if (s == 0) {
        float o0 = a0 * a0;
        float o1 = a1x * a1x + a1y * a1y + a1z * a1z;
        float o2 = axx * axx + ayy * ayy + azz * azz
                 + 2.0f * (axy * axy + axz * axz + ayz * ayz);
        float* o = out + (size_t)t * 24;
        o[m] = o0; o[8 + m] = o1; o[16 + m] = o2;
    }
}

// ---------------------------------------------------------------------------
extern "C" void kernel_launch(void* const* d_in, const int* in_sizes, int n_in,
                              void* d_out, int out_size, void* d_ws, size_t ws_size,
                              hipStream_t stream)
{
    const float* cart       = (const float*)d_in[0];
    const int*   species    = (const int*)  d_in[2];
    const int*   atom_index = (const int*)  d_in[3];
    const float* shifts     = (const float*)d_in[4];
    const float* rs         = (const float*)d_in[5];
    const float* inta       = (const float*)d_in[6];
    const float* params     = (const float*)d_in[7];
    const float* hyper      = (const float*)d_in[8];

    const int B  = in_sizes[1];          // 8
    const int N  = in_sizes[2] / B;      // 1000
    const int BP = in_sizes[3] / 2;      // 320000
    const int P  = BP / B;               // 40000
    const int T  = B * N;                // 8000

    char* ws = (char*)d_ws;
    float4* payload = (float4*)ws;                       // T*CAP*16 = 32.8 MB
    int*    cursors = (int*)(ws + (size_t)T * CAP * 16); // T ints

    hipMemsetAsync(cursors, 0, (size_t)T * sizeof(int), stream);

    dim3 fgrid((P + 255) / 256, B);
    fill_binned_kernel<<<fgrid, 256, 0, stream>>>(
        cart, species, atom_index, shifts, cursors, payload, BP, P, N);

    atom_gather_kernel<<<(T + 3) / 4, 256, 0, stream>>>(
        payload, cursors, rs, inta, params, hyper, (float*)d_out, T);
}